// Round 1
// baseline (4995.293 us; speedup 1.0000x reference)
//
#include <hip/hip_runtime.h>
#include <cstdint>
#include <cstddef>

// Problem constants (fixed by the reference)
#define T_STEPS 256
#define BATCH   256
#define DIN     512
#define HID     1024
#define KTOT    1536   // DIN + HID
#define NOUT    4096   // 4*HID

typedef __bf16 bf16;
typedef __bf16 bf16x4 __attribute__((ext_vector_type(4)));
typedef __bf16 bf16x8 __attribute__((ext_vector_type(8)));
typedef float  f32x4  __attribute__((ext_vector_type(4)));

// ---------------------------------------------------------------------------
// async global->LDS, 16B per lane (wave-uniform LDS base + lane*16 by HW)
__device__ __forceinline__ void gload16(const void* g, void* l) {
  __builtin_amdgcn_global_load_lds(
      (const __attribute__((address_space(1))) void*)g,
      (__attribute__((address_space(3))) void*)l, 16, 0, 0);
}

// ---------------------------------------------------------------------------
// Build Wt [NOUT][KTOT] bf16 (transposed, gate-concatenated):
//   Wt[n][k] = W_gate(n>>10)[k][n&1023]
__global__ void convert_w_kernel(const float* __restrict__ Wf, const float* __restrict__ Wi,
                                 const float* __restrict__ Wg, const float* __restrict__ Wo,
                                 bf16* __restrict__ Wt) {
  __shared__ float tile[64][65];
  const int k0 = blockIdx.x * 64;   // 24 blocks
  const int n0 = blockIdx.y * 64;   // 64 blocks
  const int g  = n0 >> 10;
  const float* src = (g == 0) ? Wf : (g == 1) ? Wi : (g == 2) ? Wg : Wo;
  const int j0 = n0 & 1023;
  const int t  = threadIdx.x;       // 256
  const int tj = t & 63, tr = t >> 6;  // tr in 0..3
#pragma unroll
  for (int r = 0; r < 16; ++r) {
    int kl = r * 4 + tr;
    tile[kl][tj] = src[(size_t)(k0 + kl) * HID + (j0 + tj)];
  }
  __syncthreads();
#pragma unroll
  for (int r = 0; r < 16; ++r) {
    int nl = r * 4 + tr;
    Wt[(size_t)(n0 + nl) * KTOT + (k0 + tj)] = (bf16)tile[tj][nl];
  }
}

// ---------------------------------------------------------------------------
// fp32 -> bf16 convert of one timestep slice (grid.y = t)
__global__ void convert_x_kernel(const float* __restrict__ X,
                                 char* __restrict__ xb_base, size_t xb_stride_bytes) {
  const int t = blockIdx.y;
  const int i = blockIdx.x * blockDim.x + threadIdx.x;  // 0 .. B*D/4-1 (32768)
  const float4 v = ((const float4*)(X + (size_t)t * BATCH * DIN))[i];
  bf16x4 o;
  o[0] = (bf16)v.x; o[1] = (bf16)v.y; o[2] = (bf16)v.z; o[3] = (bf16)v.w;
  ((bf16x4*)(xb_base + (size_t)t * xb_stride_bytes))[i] = o;
}

// ---------------------------------------------------------------------------
// Per-step GEMM: C[M=256][N=4096] = A @ W, K=1536.
// A rows: k<K0 from A0 (lda0), k>=K0 from A1 (lda1). B is Wt [NOUT][KTOT] (B^T layout).
// Tiles: BM=BN=BK=64, 256 threads = 4 waves (2x2), each wave 32x32 out.
#define BM 64
#define BN 64
#define BK 64
#define NBX (NOUT / BN)   // 64

__global__ __launch_bounds__(256)
void step_gemm_kernel(const bf16* __restrict__ A0, int lda0, int K0,
                      const bf16* __restrict__ A1, int lda1,
                      const bf16* __restrict__ Bt,
                      float* __restrict__ C, int K) {
  __shared__ bf16 lds[2][2][BM * BK];   // [buf][A=0/B=1][64*64]  = 32 KiB total
  const int tid  = threadIdx.x;
  const int lane = tid & 63;
  const int wid  = tid >> 6;            // 0..3
  const int wm   = wid >> 1, wn = wid & 1;
  const int bx   = blockIdx.x & (NBX - 1);
  const int by   = blockIdx.x >> 6;
  const int bm0  = by * BM, bn0 = bx * BN;
  const int nk   = K / BK;

  f32x4 acc[2][2] = {};

  auto stage = [&](int buf, int kt) {
    const int k0 = kt * BK;
    const bf16* As; int lda; int kl;
    if (k0 < K0) { As = A0; lda = lda0; kl = k0; }
    else         { As = A1; lda = lda1; kl = k0 - K0; }
    // A tile: 8 KiB = 8 chunks of 1 KiB; wave w stages chunks w and w+4
#pragma unroll
    for (int cc = 0; cc < 2; ++cc) {
      const int chunk = wid + cc * 4;
      const int row   = chunk * 8 + (lane >> 3);
      const int kk    = kl + ((lane & 7) << 3);
      gload16(As + (size_t)(bm0 + row) * lda + kk, &lds[buf][0][chunk * 512]);
    }
    // B tile from Wt (rows = n, contiguous k)
#pragma unroll
    for (int cc = 0; cc < 2; ++cc) {
      const int chunk = wid + cc * 4;
      const int n     = chunk * 8 + (lane >> 3);
      const int kk    = k0 + ((lane & 7) << 3);
      gload16(Bt + (size_t)(bn0 + n) * KTOT + kk, &lds[buf][1][chunk * 512]);
    }
  };

  stage(0, 0);
  asm volatile("s_waitcnt vmcnt(0)" ::: "memory");
  __syncthreads();

  for (int kt = 0; kt < nk; ++kt) {
    const int buf = kt & 1;
    if (kt + 1 < nk) stage(buf ^ 1, kt + 1);

    const bf16* Al = &lds[buf][0][0];
    const bf16* Bl = &lds[buf][1][0];
    const int arow = wm * 32 + (lane & 15);
    const int brow = wn * 32 + (lane & 15);
    const int koff = (lane >> 4) << 3;
#pragma unroll
    for (int kk = 0; kk < 2; ++kk) {
      bf16x8 a0 = *(const bf16x8*)(Al + (size_t)arow        * BK + kk * 32 + koff);
      bf16x8 a1 = *(const bf16x8*)(Al + (size_t)(arow + 16) * BK + kk * 32 + koff);
      bf16x8 b0 = *(const bf16x8*)(Bl + (size_t)brow        * BK + kk * 32 + koff);
      bf16x8 b1 = *(const bf16x8*)(Bl + (size_t)(brow + 16) * BK + kk * 32 + koff);
      acc[0][0] = __builtin_amdgcn_mfma_f32_16x16x32_bf16(a0, b0, acc[0][0], 0, 0, 0);
      acc[0][1] = __builtin_amdgcn_mfma_f32_16x16x32_bf16(a0, b1, acc[0][1], 0, 0, 0);
      acc[1][0] = __builtin_amdgcn_mfma_f32_16x16x32_bf16(a1, b0, acc[1][0], 0, 0, 0);
      acc[1][1] = __builtin_amdgcn_mfma_f32_16x16x32_bf16(a1, b1, acc[1][1], 0, 0, 0);
    }
    asm volatile("s_waitcnt vmcnt(0)" ::: "memory");
    __syncthreads();
  }

  // Epilogue: C/D layout col=lane&15, row=(lane>>4)*4+r  (m89-verified)
  const int crow0 = bm0 + wm * 32 + ((lane >> 4) << 2);
  const int ccol0 = bn0 + wn * 32 + (lane & 15);
#pragma unroll
  for (int mi = 0; mi < 2; ++mi)
#pragma unroll
    for (int ni = 0; ni < 2; ++ni)
#pragma unroll
      for (int r = 0; r < 4; ++r) {
        const int m = crow0 + mi * 16 + r;
        const int n = ccol0 + ni * 16;
        C[(size_t)m * NOUT + n] = acc[mi][ni][r];
      }
}

// ---------------------------------------------------------------------------
// Gates: z -> (f,i,g,o) -> c,h. Writes fp32 out slice + bf16 h for next step.
__global__ void gate_kernel(const float* __restrict__ z,
                            const float* __restrict__ bf_, const float* __restrict__ bi_,
                            const float* __restrict__ bg_, const float* __restrict__ bo_,
                            float* __restrict__ c, bf16* __restrict__ hb,
                            float* __restrict__ out_h) {
  const int idx = blockIdx.x * blockDim.x + threadIdx.x;   // 0 .. B*H-1
  const int b = idx >> 10;
  const int j = idx & 1023;
  const float* zr = z + (size_t)b * NOUT;
  const float zf = zr[j]            + bf_[j];
  const float zi = zr[j + HID]      + bi_[j];
  const float zg = zr[j + 2 * HID]  + bg_[j];
  const float zo = zr[j + 3 * HID]  + bo_[j];
  const float f = 1.f / (1.f + expf(-zf));
  const float i = 1.f / (1.f + expf(-zi));
  const float g = tanhf(zg);
  const float o = 1.f / (1.f + expf(-zo));
  const float cn = f * c[idx] + i * g;
  c[idx] = cn;
  const float h = o * tanhf(cn);
  out_h[idx] = h;
  hb[idx] = (bf16)h;
}

// ---------------------------------------------------------------------------
extern "C" void kernel_launch(void* const* d_in, const int* in_sizes, int n_in,
                              void* d_out, int out_size, void* d_ws, size_t ws_size,
                              hipStream_t stream) {
  const float* X   = (const float*)d_in[0];
  const float* Wf  = (const float*)d_in[1];
  const float* bf_ = (const float*)d_in[2];
  const float* Wi  = (const float*)d_in[3];
  const float* bi_ = (const float*)d_in[4];
  const float* Wg  = (const float*)d_in[5];
  const float* bg_ = (const float*)d_in[6];
  const float* Wo  = (const float*)d_in[7];
  const float* bo_ = (const float*)d_in[8];
  float* out = (float*)d_out;

  // workspace layout
  char* ws = (char*)d_ws;
  const size_t WtB = (size_t)NOUT * KTOT * 2;            // 12.58 MB
  const size_t hbB = (size_t)BATCH * HID * 2;            // 0.5 MB
  const size_t cB  = (size_t)BATCH * HID * 4;            // 1 MB
  const size_t zB  = (size_t)BATCH * NOUT * 4;           // 4 MB
  const size_t XbB = (size_t)T_STEPS * BATCH * DIN * 2;  // 67 MB

  bf16*  Wt = (bf16*)ws;              ws += WtB;
  bf16*  hb = (bf16*)ws;              ws += hbB;
  float* c  = (float*)(void*)ws;      ws += cB;
  float* z  = (float*)(void*)ws;      ws += zB;

  // X in bf16: prefer workspace; if ws too small, stash X_t slices inside the
  // (not yet written) d_out slices. Slice t is read by GEMM t strictly before
  // gate t overwrites that region (stream-ordered), so this is safe.
  char*  xb_base;
  size_t xb_stride;
  const size_t base_need = WtB + hbB + cB + zB;
  if (ws_size >= base_need + XbB) {
    xb_base   = ws;
    xb_stride = (size_t)BATCH * DIN * 2;   // packed
  } else {
    xb_base   = (char*)d_out;
    xb_stride = (size_t)BATCH * HID * 4;   // one output slice per t (1 MB each)
  }

  // h0 = c0 = 0 (hb and c are adjacent)
  hipMemsetAsync(hb, 0, hbB + cB, stream);

  convert_w_kernel<<<dim3(KTOT / 64, NOUT / 64), 256, 0, stream>>>(Wf, Wi, Wg, Wo, Wt);
  convert_x_kernel<<<dim3(BATCH * DIN / 4 / 256, T_STEPS), 256, 0, stream>>>(X, xb_base, xb_stride);

  for (int t = 0; t < T_STEPS; ++t) {
    const bf16* A0 = (const bf16*)(xb_base + (size_t)t * xb_stride);
    step_gemm_kernel<<<(BATCH / BM) * NBX, 256, 0, stream>>>(
        A0, DIN, DIN, hb, HID, Wt, z, KTOT);
    gate_kernel<<<BATCH * HID / 256, 256, 0, stream>>>(
        z, bf_, bi_, bg_, bo_, c, hb, out + (size_t)t * BATCH * HID);
  }

  // hx = outputs[T-1]; cx = final c
  hipMemcpyAsync(out + (size_t)T_STEPS * BATCH * HID,
                 out + (size_t)(T_STEPS - 1) * BATCH * HID,
                 (size_t)BATCH * HID * 4, hipMemcpyDeviceToDevice, stream);
  hipMemcpyAsync(out + (size_t)T_STEPS * BATCH * HID + (size_t)BATCH * HID,
                 c, (size_t)BATCH * HID * 4, hipMemcpyDeviceToDevice, stream);
}

// Round 2
// 2989.028 us; speedup vs baseline: 1.6712x; 1.6712x over previous
//
#include <hip/hip_runtime.h>
#include <cstdint>
#include <cstddef>

// Problem constants (fixed by the reference)
#define T_STEPS 256
#define BATCH   256
#define DIN     512
#define HID     1024
#define KTOT    1536   // DIN + HID
#define NOUT    4096   // 4*HID

typedef __bf16 bf16;
typedef __bf16 bf16x4 __attribute__((ext_vector_type(4)));
typedef __bf16 bf16x8 __attribute__((ext_vector_type(8)));
typedef float  f32x4  __attribute__((ext_vector_type(4)));

// ---------------------------------------------------------------------------
// async global->LDS, 16B per lane (HW: wave-uniform LDS base + lane*16)
__device__ __forceinline__ void gload16(const void* g, void* l) {
  __builtin_amdgcn_global_load_lds(
      (const __attribute__((address_space(1))) void*)g,
      (__attribute__((address_space(3))) void*)l, 16, 0, 0);
}

// ---------------------------------------------------------------------------
// Gate-interleaved transposed weights:
//   Wt2[row][k], row = (j>>4)*64 + gate*16 + (j&15), value = W_gate[k][j]
// So a 64-row slice = 16 j's x 4 gates; MFMA fragment ni (16 cols) = gate ni.
__global__ void convert_w_kernel(const float* __restrict__ Wf, const float* __restrict__ Wi,
                                 const float* __restrict__ Wg, const float* __restrict__ Wo,
                                 bf16* __restrict__ Wt) {
  __shared__ float tile[64][17];
  const int k0 = blockIdx.x * 64;    // 24 blocks
  const int jb = blockIdx.y;         // 64 blocks
  const int j0 = jb * 16;
  const int t  = threadIdx.x;        // 256
  const float* srcs[4] = {Wf, Wi, Wg, Wo};
#pragma unroll
  for (int g = 0; g < 4; ++g) {
    const float* src = srcs[g];
    {
      const int jl = t & 15, kb = t >> 4;   // kb 0..15
#pragma unroll
      for (int r = 0; r < 4; ++r) {
        const int kl = kb + 16 * r;
        tile[kl][jl] = src[(size_t)(k0 + kl) * HID + (j0 + jl)];
      }
    }
    __syncthreads();
    {
      const int kk = t & 63, jl4 = t >> 6;  // jl4 0..3
#pragma unroll
      for (int r = 0; r < 4; ++r) {
        const int jl = jl4 + 4 * r;
        Wt[(size_t)(jb * 64 + g * 16 + jl) * KTOT + (k0 + kk)] = (bf16)tile[kk][jl];
      }
    }
    __syncthreads();
  }
}

// ---------------------------------------------------------------------------
// fp32 -> bf16 convert of one timestep slice (grid.y = t)
__global__ void convert_x_kernel(const float* __restrict__ X,
                                 char* __restrict__ xb_base, size_t xb_stride_bytes) {
  const int t = blockIdx.y;
  const int i = blockIdx.x * blockDim.x + threadIdx.x;  // 0 .. B*D/4-1
  const float4 v = ((const float4*)(X + (size_t)t * BATCH * DIN))[i];
  bf16x4 o;
  o[0] = (bf16)v.x; o[1] = (bf16)v.y; o[2] = (bf16)v.z; o[3] = (bf16)v.w;
  ((bf16x4*)(xb_base + (size_t)t * xb_stride_bytes))[i] = o;
}

// ---------------------------------------------------------------------------
// Fused LSTM step: z = [x_t | h_{t-1}] @ W + b, gates, c/h update.
// Tiles: BM=BN=64, BK=64, 4 waves; wave wid owns rows wid*16..+16 of the
// 64-row M-tile and all 64 cols (= 16 j x 4 gates). acc[ni] : gate ni.
// Pipeline: 4 LDS buffers, 3-deep prefetch, counted vmcnt, 1 barrier/K-tile.
#define BK   64
#define NK   (KTOT / BK)   // 24
#define NBUF 4

__global__ __launch_bounds__(256)
void lstm_step_kernel(const bf16* __restrict__ A0,    // x_t   [BATCH][DIN]
                      const bf16* __restrict__ Aprev, // h_{t-1}[BATCH][HID]
                      const bf16* __restrict__ Bt,    // Wt2 [NOUT][KTOT]
                      const float* __restrict__ bf_, const float* __restrict__ bi_,
                      const float* __restrict__ bg_, const float* __restrict__ bo_,
                      float* __restrict__ c,          // [BATCH][HID] in/out
                      bf16* __restrict__ hnext,       // h_t bf16
                      float* __restrict__ out_h) {    // outputs[t]
  __shared__ bf16 lds[NBUF][2][64 * 64];  // 64 KiB
  const int tid  = threadIdx.x;
  const int lane = tid & 63;
  const int wid  = tid >> 6;

  // XCD-aware bijective swizzle: XCD x owns N-blocks 8x..8x+7 (j-slice of 128)
  // -> its 1.57 MB B-panel stays resident in that XCD's 4 MB L2 across steps.
  const int bid  = blockIdx.x;        // 0..255
  const int xcd  = bid & 7;
  const int slot = bid >> 3;          // 0..31
  const int nblk = xcd * 8 + (slot & 7);  // 0..63
  const int mblk = slot >> 3;             // 0..3
  const int bm0  = mblk * 64;
  const int bn0  = nblk * 64;

  // staging geometry: chunk = 8 rows x 64 k (1 KiB); lane l -> row l>>3,
  // k-slot (l&7)^(l>>3) (pre-swizzled source => XOR-swizzled LDS content,
  // linear gload_lds destination — rule #21 compliant)
  const int lrow  = lane >> 3;
  const int kslot = (lane & 7) ^ lrow;

  f32x4 acc[4] = {};

  auto stage = [&](int buf, int kt) {
    const int k0 = kt * BK;
    const bf16* As; int lda; int kb;
    if (k0 < DIN) { As = A0;    lda = DIN; kb = k0; }
    else          { As = Aprev; lda = HID; kb = k0 - DIN; }
#pragma unroll
    for (int cc = 0; cc < 2; ++cc) {
      const int chunk = wid + cc * 4;       // 8 chunks over 4 waves
      const int row   = chunk * 8 + lrow;
      gload16(As + (size_t)(bm0 + row) * lda + kb + kslot * 8,
              &lds[buf][0][chunk * 512]);
      gload16(Bt + (size_t)(bn0 + row) * KTOT + k0 + kslot * 8,
              &lds[buf][1][chunk * 512]);
    }
  };

  stage(0, 0); stage(1, 1); stage(2, 2);   // 12 loads in flight per wave

  const int frow = lane & 15;
  const int kro  = (lane >> 4) << 3;       // 0,8,16,24 (bf16 elems)
  const int arow = wid * 16 + frow;
  const int aswz = (arow & 7) << 3;        // XOR swizzle (elems) for A row
  const int bswz = (frow & 7) << 3;        // for B rows (row&7 == frow&7)

  for (int kt = 0; kt < NK; ++kt) {
    // own loads for tile kt done; tiles kt+1,kt+2 (4 loads each) stay in flight
    if (kt < NK - 2)       asm volatile("s_waitcnt vmcnt(8)" ::: "memory");
    else if (kt == NK - 2) asm volatile("s_waitcnt vmcnt(4)" ::: "memory");
    else                   asm volatile("s_waitcnt vmcnt(0)" ::: "memory");
    __builtin_amdgcn_s_barrier();          // all waves' tile-kt chunks landed
    __builtin_amdgcn_sched_barrier(0);
    if (kt + 3 < NK) stage((kt + 3) & 3, kt + 3);  // overwrites buf (kt-1)&3: safe

    const bf16* Al = &lds[kt & 3][0][0];
    const bf16* Bl = &lds[kt & 3][1][0];
#pragma unroll
    for (int kk = 0; kk < 2; ++kk) {
      const bf16x8 a = *(const bf16x8*)(Al + arow * 64 + ((kk * 32 + kro) ^ aswz));
#pragma unroll
      for (int ni = 0; ni < 4; ++ni) {
        const bf16x8 b = *(const bf16x8*)(Bl + (ni * 16 + frow) * 64 + ((kk * 32 + kro) ^ bswz));
        acc[ni] = __builtin_amdgcn_mfma_f32_16x16x32_bf16(a, b, acc[ni], 0, 0, 0);
      }
    }
  }

  // Epilogue: C/D layout col=lane&15, row=(lane>>4)*4+r. ni = gate.
  // Per lane: j = nblk*16 + frow, rows m = bm0 + wid*16 + (lane>>4)*4 + r.
  const int j  = (bn0 >> 2) + frow;        // nblk*16 + frow
  const int r0 = (lane >> 4) << 2;
  const float bfv = bf_[j], biv = bi_[j], bgv = bg_[j], bov = bo_[j];
#pragma unroll
  for (int r = 0; r < 4; ++r) {
    const int m = bm0 + wid * 16 + r0 + r;
    const size_t idx = (size_t)m * HID + j;
    const float f = 1.f / (1.f + expf(-(acc[0][r] + bfv)));
    const float i = 1.f / (1.f + expf(-(acc[1][r] + biv)));
    const float g = tanhf(acc[2][r] + bgv);
    const float o = 1.f / (1.f + expf(-(acc[3][r] + bov)));
    const float cn = f * c[idx] + i * g;
    c[idx] = cn;
    const float h = o * tanhf(cn);
    out_h[idx] = h;
    hnext[idx] = (bf16)h;
  }
}

// ---------------------------------------------------------------------------
extern "C" void kernel_launch(void* const* d_in, const int* in_sizes, int n_in,
                              void* d_out, int out_size, void* d_ws, size_t ws_size,
                              hipStream_t stream) {
  const float* X   = (const float*)d_in[0];
  const float* Wf  = (const float*)d_in[1];
  const float* bf_ = (const float*)d_in[2];
  const float* Wi  = (const float*)d_in[3];
  const float* bi_ = (const float*)d_in[4];
  const float* Wg  = (const float*)d_in[5];
  const float* bg_ = (const float*)d_in[6];
  const float* Wo  = (const float*)d_in[7];
  const float* bo_ = (const float*)d_in[8];
  float* out = (float*)d_out;

  const size_t BH  = (size_t)BATCH * HID;
  const size_t WtB = (size_t)NOUT * KTOT * 2;            // 12.58 MB
  const size_t hbB = BH * 2;                             // 0.5 MB
  const size_t cB  = BH * 4;                             // 1 MB
  const size_t XbB = (size_t)T_STEPS * BATCH * DIN * 2;  // 67 MB

  char* ws = (char*)d_ws;
  bf16*  Wt  = (bf16*)ws;              ws += WtB;
  bf16*  hb0 = (bf16*)ws;              ws += hbB;   // h ping
  bf16*  hb1 = (bf16*)ws;              ws += hbB;   // h pong
  float* c   = (float*)(void*)ws;      ws += cB;

  // X in bf16: prefer workspace; else stash slice t inside out slice t+1
  // (read at step t, overwritten only by step t+1's epilogue — stream-ordered).
  char*  xb_base;
  size_t xb_stride;
  const size_t base_need = WtB + 2 * hbB + cB;
  if (ws_size >= base_need + XbB) {
    xb_base   = ws;
    xb_stride = (size_t)BATCH * DIN * 2;   // packed 256 KB slices
  } else {
    xb_base   = (char*)d_out + BH * 4;     // slot t+1 (slot 256 = hx region)
    xb_stride = BH * 4;                    // 1 MB slots
  }

  // h0 = 0 (hb0), c0 = 0; hb1 is written before first read.
  hipMemsetAsync(hb0, 0, hbB, stream);
  hipMemsetAsync(c, 0, cB, stream);

  convert_w_kernel<<<dim3(KTOT / 64, NOUT / 64), 256, 0, stream>>>(Wf, Wi, Wg, Wo, Wt);
  convert_x_kernel<<<dim3(BATCH * DIN / 4 / 256, T_STEPS), 256, 0, stream>>>(X, xb_base, xb_stride);

  for (int t = 0; t < T_STEPS; ++t) {
    const bf16* A0    = (const bf16*)(xb_base + (size_t)t * xb_stride);
    const bf16* hprev = (t & 1) ? hb1 : hb0;
    bf16*       hnext = (t & 1) ? hb0 : hb1;
    lstm_step_kernel<<<256, 256, 0, stream>>>(
        A0, hprev, Wt, bf_, bi_, bg_, bo_, c, hnext, out + (size_t)t * BH);
  }

  // hx = outputs[T-1]; cx = final c
  hipMemcpyAsync(out + (size_t)T_STEPS * BH, out + (size_t)(T_STEPS - 1) * BH,
                 BH * 4, hipMemcpyDeviceToDevice, stream);
  hipMemcpyAsync(out + (size_t)T_STEPS * BH + BH, c,
                 BH * 4, hipMemcpyDeviceToDevice, stream);
}